// Round 1
// baseline (371.626 us; speedup 1.0000x reference)
//
#include <hip/hip_runtime.h>

// MoE with vocab-factorized precompute:
//   T0[e][v][d] = emb0[v] @ W1[e, :1024, :] + b1[e]   (bf16)
//   T1[e][v][d] = emb1[v] @ W1[e, 1024:, :]           (bf16)
//   G0/G1[v][e] = gating partial logits               (f32, bg in G0)
//   out[b] = sum_e g_e * (silu(T0[e][x0]+T1[e][x1]) @ W2[e] + b2[e])
// Layer-2 done as one fused M=65536,K=4096,N=128 bf16 MFMA GEMM with gates
// folded into the A operand.

#define NTOK 65536

typedef __attribute__((ext_vector_type(8))) short short8;
typedef __attribute__((ext_vector_type(4))) float f32x4;

__device__ __forceinline__ unsigned short f2b(float f) {
  unsigned int u = __builtin_bit_cast(unsigned int, f);
  u += 0x7fffu + ((u >> 16) & 1u);            // RNE to bf16
  return (unsigned short)(u >> 16);
}
__device__ __forceinline__ float bflo(unsigned int u) {
  return __builtin_bit_cast(float, u << 16);
}
__device__ __forceinline__ float bfhi(unsigned int u) {
  return __builtin_bit_cast(float, u & 0xffff0000u);
}

// ---------------- gating tables (pure f32) ----------------
__global__ void prep_g(const float* __restrict__ emb0, const float* __restrict__ emb1,
                       const float* __restrict__ Wg, const float* __restrict__ bg,
                       float* __restrict__ G0, float* __restrict__ G1) {
  const int bid = blockIdx.x;           // 0..1023
  const int half = bid >> 9;
  const int v = bid & 511;
  const float* __restrict__ emb = half ? emb1 : emb0;
  const float* __restrict__ wg = Wg + (size_t)half * 1024 * 4;
  float a0 = 0.f, a1 = 0.f, a2 = 0.f, a3 = 0.f;
  for (int i = threadIdx.x; i < 1024; i += 256) {
    const float ev = emb[(size_t)v * 1024 + i];
    const float4 w = *(const float4*)(wg + (size_t)i * 4);
    a0 += ev * w.x; a1 += ev * w.y; a2 += ev * w.z; a3 += ev * w.w;
  }
  __shared__ float red[4][256];
  red[0][threadIdx.x] = a0; red[1][threadIdx.x] = a1;
  red[2][threadIdx.x] = a2; red[3][threadIdx.x] = a3;
  __syncthreads();
  for (int s = 128; s > 0; s >>= 1) {
    if (threadIdx.x < s) {
      red[0][threadIdx.x] += red[0][threadIdx.x + s];
      red[1][threadIdx.x] += red[1][threadIdx.x + s];
      red[2][threadIdx.x] += red[2][threadIdx.x + s];
      red[3][threadIdx.x] += red[3][threadIdx.x + s];
    }
    __syncthreads();
  }
  if (threadIdx.x < 4) {
    const float val = red[threadIdx.x][0] + (half == 0 ? bg[threadIdx.x] : 0.f);
    (half ? G1 : G0)[(size_t)v * 4 + threadIdx.x] = val;
  }
}

// ---------------- W2 [4][1024][128] f32 -> W2T [128 o][4096 k] bf16 ----------------
__global__ void prep_w2(const float* __restrict__ W2, unsigned short* __restrict__ W2T) {
  __shared__ float st[64][65];
  const int kt = blockIdx.x;   // 0..63 (k tiles of 64)
  const int ot = blockIdx.y;   // 0..1  (o tiles of 64)
  const int tid = threadIdx.x;
  for (int it = 0; it < 16; ++it) {
    const int idx = it * 256 + tid;
    const int k = idx >> 6, o = idx & 63;
    st[k][o] = W2[(size_t)(kt * 64 + k) * 128 + ot * 64 + o];
  }
  __syncthreads();
  for (int it = 0; it < 4; ++it) {
    const int idx = it * 256 + tid;
    const int o = idx >> 4, c = idx & 15;
    const unsigned int p0 =
        (unsigned int)f2b(st[c * 4 + 0][o]) | ((unsigned int)f2b(st[c * 4 + 1][o]) << 16);
    const unsigned int p1 =
        (unsigned int)f2b(st[c * 4 + 2][o]) | ((unsigned int)f2b(st[c * 4 + 3][o]) << 16);
    *(uint2*)(W2T + (size_t)(ot * 64 + o) * 4096 + kt * 64 + c * 4) = make_uint2(p0, p1);
  }
}

// ---------------- expert tables: 8 GEMMs of 512x1024x1024 (bf16 MFMA) ----------------
__launch_bounds__(256, 2)
__global__ void build_tables(const float* __restrict__ emb0, const float* __restrict__ emb1,
                             const float* __restrict__ W1, const float* __restrict__ b1,
                             unsigned short* __restrict__ T0, unsigned short* __restrict__ T1) {
  const int z = blockIdx.y;            // 0..7 : e*2 + half
  const int e = z >> 1, half = z & 1;
  const int vt = blockIdx.x >> 3;      // 0..3  (v tile of 128)
  const int dt = blockIdx.x & 7;       // 0..7  (d tile of 128)
  const float* __restrict__ embA = half ? emb1 : emb0;
  const float* __restrict__ W = W1 + ((size_t)e * 2048 + (size_t)half * 1024) * 1024;
  unsigned short* __restrict__ Tout = (half ? T1 : T0) + (size_t)e * 512 * 1024;

  __shared__ unsigned short Atile[128 * 64];   // [v][k] bf16, XOR-swizzled, 16KB
  __shared__ unsigned short Btile[128 * 64];   // [d][k] bf16 (B^T), swizzled, 16KB

  const int tid = threadIdx.x, lane = tid & 63, wave = tid >> 6;
  const int wm = wave >> 1, wn = wave & 1;

  f32x4 acc[4][4] = {};

  const int arow = tid >> 3, ac = tid & 7;     // staging: rows arow+32q, 16B chunk ac
  int awoff[4];
#pragma unroll
  for (int q = 0; q < 4; ++q) {
    const int r = arow + 32 * q;
    awoff[q] = r * 128 + ((ac * 16) ^ ((r & 7) << 4));
  }
  const int lh16 = (lane >> 4) * 16;
  int aoff[4], asw[4], boff[4], bsw[4];
#pragma unroll
  for (int i = 0; i < 4; ++i) {
    const int ra = wm * 64 + i * 16 + (lane & 15);
    aoff[i] = ra * 128; asw[i] = (ra & 7) << 4;
    const int rb = wn * 64 + i * 16 + (lane & 15);
    boff[i] = rb * 128; bsw[i] = (rb & 7) << 4;
  }

  for (int kt = 0; kt < 16; ++kt) {
    const int k0 = kt * 64;
    __syncthreads();   // previous iteration's frag reads complete
    // A: emb rows, f32 -> bf16
#pragma unroll
    for (int q = 0; q < 4; ++q) {
      const float* src = embA + (size_t)(vt * 128 + arow + 32 * q) * 1024 + k0 + ac * 8;
      const float4 lo = *(const float4*)src;
      const float4 hi = *(const float4*)(src + 4);
      short8 o;
      o[0] = (short)f2b(lo.x); o[1] = (short)f2b(lo.y);
      o[2] = (short)f2b(lo.z); o[3] = (short)f2b(lo.w);
      o[4] = (short)f2b(hi.x); o[5] = (short)f2b(hi.y);
      o[6] = (short)f2b(hi.z); o[7] = (short)f2b(hi.w);
      *(short8*)((char*)Atile + awoff[q]) = o;
    }
    // B^T: strided column reads of W (L2/L3 resident; prep-class cost)
#pragma unroll
    for (int q = 0; q < 4; ++q) {
      const int dd = arow + 32 * q;
      const float* wsrc = W + (size_t)(k0 + ac * 8) * 1024 + dt * 128 + dd;
      short8 o;
#pragma unroll
      for (int j = 0; j < 8; ++j) o[j] = (short)f2b(wsrc[(size_t)j * 1024]);
      *(short8*)((char*)Btile + awoff[q]) = o;
    }
    __syncthreads();
    const char* Ab = (const char*)Atile;
    const char* Bb = (const char*)Btile;
#pragma unroll
    for (int kk = 0; kk < 2; ++kk) {
      const int kb = kk * 64 + lh16;
      short8 af[4], bfr[4];
#pragma unroll
      for (int mi = 0; mi < 4; ++mi) af[mi] = *(const short8*)(Ab + aoff[mi] + (kb ^ asw[mi]));
#pragma unroll
      for (int ni = 0; ni < 4; ++ni) bfr[ni] = *(const short8*)(Bb + boff[ni] + (kb ^ bsw[ni]));
#pragma unroll
      for (int mi = 0; mi < 4; ++mi)
#pragma unroll
        for (int ni = 0; ni < 4; ++ni)
          acc[mi][ni] = __builtin_amdgcn_mfma_f32_16x16x32_bf16(af[mi], bfr[ni], acc[mi][ni], 0, 0, 0);
    }
  }
  // epilogue: + b1 (half 0 only), bf16 store
  const float* bb = b1 + (size_t)e * 1024;
#pragma unroll
  for (int ni = 0; ni < 4; ++ni) {
    const int dcol = dt * 128 + wn * 64 + ni * 16 + (lane & 15);
    const float bias = (half == 0) ? bb[dcol] : 0.f;
#pragma unroll
    for (int mi = 0; mi < 4; ++mi) {
      const int vrow0 = vt * 128 + wm * 64 + mi * 16 + ((lane >> 4) << 2);
      const f32x4 a = acc[mi][ni];
#pragma unroll
      for (int j = 0; j < 4; ++j)
        Tout[(size_t)(vrow0 + j) * 1024 + dcol] = f2b(a[j] + bias);
    }
  }
}

// ---------------- main fused kernel: gather + silu + gate + GEMM ----------------
__launch_bounds__(256, 2)
__global__ void moe_main(const int* __restrict__ X,
                         const unsigned short* __restrict__ T0,
                         const unsigned short* __restrict__ T1,
                         const unsigned short* __restrict__ W2T,
                         const float* __restrict__ G0,
                         const float* __restrict__ G1,
                         const float* __restrict__ b2v,
                         float* __restrict__ out) {
  __shared__ unsigned short Atile[2][128 * 64];
  __shared__ unsigned short Btile[2][128 * 64];
  __shared__ float gl[128 * 4];
  __shared__ int xs0[128], xs1[128];

  const int tid = threadIdx.x, lane = tid & 63, wave = tid >> 6;
  const int wm = wave >> 1, wn = wave & 1;
  const int b0 = blockIdx.x * 128;

  if (tid < 128) {
    const int b = b0 + tid;
    const int x0 = X[2 * b], x1 = X[2 * b + 1];
    xs0[tid] = x0; xs1[tid] = x1;
    const float4 l0 = *(const float4*)(G0 + 4 * x0);
    const float4 l1 = *(const float4*)(G1 + 4 * x1);
    const float z0 = l0.x + l1.x, z1 = l0.y + l1.y;
    const float z2 = l0.z + l1.z, z3 = l0.w + l1.w;
    const float m = fmaxf(fmaxf(z0, z1), fmaxf(z2, z3));
    const float e0 = __expf(z0 - m), e1 = __expf(z1 - m);
    const float e2 = __expf(z2 - m), e3 = __expf(z3 - m);
    const float inv = __builtin_amdgcn_rcpf(e0 + e1 + e2 + e3);
    *(float4*)(&gl[4 * tid]) = make_float4(e0 * inv, e1 * inv, e2 * inv, e3 * inv);
  }
  __syncthreads();

  const int arow = tid >> 3, ac = tid & 7;
  int xr0[4], xr1[4], awoff[4];
  float4 gr[4];
#pragma unroll
  for (int q = 0; q < 4; ++q) {
    const int r = arow + 32 * q;
    xr0[q] = xs0[r]; xr1[q] = xs1[r];
    gr[q] = *(const float4*)(&gl[4 * r]);
    awoff[q] = r * 128 + ((ac * 16) ^ ((r & 7) << 4));
  }

  const int lh16 = (lane >> 4) * 16;
  int aoff[4], asw[4], boff[4], bsw[4];
#pragma unroll
  for (int i = 0; i < 4; ++i) {
    const int ra = wm * 64 + i * 16 + (lane & 15);
    aoff[i] = ra * 128; asw[i] = (ra & 7) << 4;
    const int rb = wn * 64 + i * 16 + (lane & 15);
    boff[i] = rb * 128; bsw[i] = (rb & 7) << 4;
  }

  f32x4 acc[4][4] = {};
  uint4 bw[4], ua[4], ub[4];
  float gen[4];

  auto loadNext = [&](int tt) {
    const int e = tt >> 4, d0 = (tt & 15) << 6;
#pragma unroll
    for (int q = 0; q < 4; ++q) {
      const int o = arow + 32 * q;
      bw[q] = *(const uint4*)(W2T + (size_t)o * 4096 + tt * 64 + ac * 8);
      ua[q] = *(const uint4*)(T0 + (((size_t)(e * 512 + xr0[q])) << 10) + d0 + ac * 8);
      ub[q] = *(const uint4*)(T1 + (((size_t)(e * 512 + xr1[q])) << 10) + d0 + ac * 8);
      gen[q] = (e == 0) ? gr[q].x : (e == 1) ? gr[q].y : (e == 2) ? gr[q].z : gr[q].w;
    }
  };
  auto writeNext = [&](int bi) {
    char* An = (char*)Atile[bi];
    char* Bn = (char*)Btile[bi];
#pragma unroll
    for (int q = 0; q < 4; ++q) {
      *(uint4*)(Bn + awoff[q]) = bw[q];
      const float g = gen[q];
      float f[8];
      f[0] = bflo(ua[q].x) + bflo(ub[q].x);
      f[1] = bfhi(ua[q].x) + bfhi(ub[q].x);
      f[2] = bflo(ua[q].y) + bflo(ub[q].y);
      f[3] = bfhi(ua[q].y) + bfhi(ub[q].y);
      f[4] = bflo(ua[q].z) + bflo(ub[q].z);
      f[5] = bfhi(ua[q].z) + bfhi(ub[q].z);
      f[6] = bflo(ua[q].w) + bflo(ub[q].w);
      f[7] = bfhi(ua[q].w) + bfhi(ub[q].w);
      short8 o8;
#pragma unroll
      for (int i = 0; i < 8; ++i) {
        const float tv = f[i];
        const float sg = g * tv * __builtin_amdgcn_rcpf(1.f + __expf(-tv));  // g*silu
        o8[i] = (short)f2b(sg);
      }
      *(short8*)(An + awoff[q]) = o8;
    }
  };

  loadNext(0);
  writeNext(0);
  __syncthreads();

  for (int t = 0; t < 64; ++t) {
    const int buf = t & 1;
    if (t < 63) loadNext(t + 1);   // issue global loads early; hide under MFMA
    const char* Ab = (const char*)Atile[buf];
    const char* Bb = (const char*)Btile[buf];
#pragma unroll
    for (int kk = 0; kk < 2; ++kk) {
      const int kb = kk * 64 + lh16;
      short8 af[4], bfr[4];
#pragma unroll
      for (int mi = 0; mi < 4; ++mi) af[mi] = *(const short8*)(Ab + aoff[mi] + (kb ^ asw[mi]));
#pragma unroll
      for (int ni = 0; ni < 4; ++ni) bfr[ni] = *(const short8*)(Bb + boff[ni] + (kb ^ bsw[ni]));
#pragma unroll
      for (int mi = 0; mi < 4; ++mi)
#pragma unroll
        for (int ni = 0; ni < 4; ++ni)
          acc[mi][ni] = __builtin_amdgcn_mfma_f32_16x16x32_bf16(af[mi], bfr[ni], acc[mi][ni], 0, 0, 0);
    }
    if (t < 63) writeNext(buf ^ 1);
    __syncthreads();
  }

  // epilogue: + sum_e g_e*b2[e][o], f32 store
#pragma unroll
  for (int ni = 0; ni < 4; ++ni) {
    const int col = wn * 64 + ni * 16 + (lane & 15);
    const float c0 = b2v[col], c1 = b2v[128 + col];
    const float c2 = b2v[256 + col], c3 = b2v[384 + col];
#pragma unroll
    for (int mi = 0; mi < 4; ++mi) {
      const int row0 = wm * 64 + mi * 16 + ((lane >> 4) << 2);
      const f32x4 a = acc[mi][ni];
#pragma unroll
      for (int j = 0; j < 4; ++j) {
        const int row = row0 + j;
        const float4 g = *(const float4*)(&gl[4 * row]);
        out[(size_t)(b0 + row) * 128 + col] = a[j] + g.x * c0 + g.y * c1 + g.z * c2 + g.w * c3;
      }
    }
  }
}

extern "C" void kernel_launch(void* const* d_in, const int* in_sizes, int n_in,
                              void* d_out, int out_size, void* d_ws, size_t ws_size,
                              hipStream_t stream) {
  const int*   X    = (const int*)  d_in[0];
  const float* emb0 = (const float*)d_in[1];
  const float* emb1 = (const float*)d_in[2];
  const float* W1   = (const float*)d_in[3];
  const float* b1   = (const float*)d_in[4];
  const float* W2   = (const float*)d_in[5];
  const float* b2   = (const float*)d_in[6];
  const float* Wg   = (const float*)d_in[7];
  const float* bg   = (const float*)d_in[8];
  float* out = (float*)d_out;

  char* ws = (char*)d_ws;
  unsigned short* T0  = (unsigned short*)(ws);                               // 4 MB
  unsigned short* T1  = (unsigned short*)(ws + (size_t)4 * 1024 * 1024);     // 4 MB
  unsigned short* W2T = (unsigned short*)(ws + (size_t)8 * 1024 * 1024);     // 1 MB
  float* G0 = (float*)(ws + (size_t)9 * 1024 * 1024);                        // 8 KB
  float* G1 = (float*)(ws + (size_t)9 * 1024 * 1024 + 8192);                 // 8 KB

  hipLaunchKernelGGL(prep_w2, dim3(64, 2), dim3(256), 0, stream, W2, W2T);
  hipLaunchKernelGGL(prep_g, dim3(1024), dim3(256), 0, stream, emb0, emb1, Wg, bg, G0, G1);
  hipLaunchKernelGGL(build_tables, dim3(32, 8), dim3(256), 0, stream, emb0, emb1, W1, b1, T0, T1);
  hipLaunchKernelGGL(moe_main, dim3(512), dim3(256), 0, stream, X, T0, T1, W2T, G0, G1, b2, out);
}

// Round 3
// 345.997 us; speedup vs baseline: 1.0741x; 1.0741x over previous
//
#include <hip/hip_runtime.h>

// MoE, vocab-factorized:
//   T0[e][v][d] = emb0[v] @ W1[e,:1024,:] + b1[e]   (bf16, via prepped E0/W1T)
//   T1[e][v][d] = emb1[v] @ W1[e,1024:,:]           (bf16)
//   G0/G1[v][e] = gating partial logits (f32, bg folded into G0)
//   out[b] = sum_e g_e * (silu(T0[e][x0]+T1[e][x1]) @ W2[e] + b2[e])
// Layer 2 = one fused M=65536,K=4096,N=128 bf16 MFMA GEMM, gates folded into A.
// Raw barriers (lgkmcnt-only) keep prefetch loads in flight across s_barrier.

typedef __attribute__((ext_vector_type(8))) short short8;
typedef __attribute__((ext_vector_type(4))) float f32x4;

static __device__ __forceinline__ unsigned short f2b(float f) {
  unsigned int u = __builtin_bit_cast(unsigned int, f);
  u += 0x7fffu + ((u >> 16) & 1u);  // RNE to bf16
  return (unsigned short)(u >> 16);
}
static __device__ __forceinline__ float bflo(unsigned int u) {
  return __builtin_bit_cast(float, u << 16);
}
static __device__ __forceinline__ float bfhi(unsigned int u) {
  return __builtin_bit_cast(float, u & 0xffff0000u);
}

// barrier WITHOUT vmcnt drain: LDS ops ordered, global prefetch stays in flight
#define BARRIER() do { asm volatile("s_waitcnt lgkmcnt(0)" ::: "memory"); \
                       __builtin_amdgcn_s_barrier(); } while (0)

// ---------------- gating tables (pure f32) ----------------
__global__ void prep_g(const float* __restrict__ emb0, const float* __restrict__ emb1,
                       const float* __restrict__ Wg, const float* __restrict__ bg,
                       float* __restrict__ G0, float* __restrict__ G1) {
  const int bid = blockIdx.x;  // 0..1023
  const int half = bid >> 9;
  const int v = bid & 511;
  const float* __restrict__ emb = half ? emb1 : emb0;
  const float* __restrict__ wg = Wg + (size_t)half * 1024 * 4;
  float a0 = 0.f, a1 = 0.f, a2 = 0.f, a3 = 0.f;
  for (int i = threadIdx.x; i < 1024; i += 256) {
    const float ev = emb[(size_t)v * 1024 + i];
    const float4 w = *(const float4*)(wg + (size_t)i * 4);
    a0 += ev * w.x; a1 += ev * w.y; a2 += ev * w.z; a3 += ev * w.w;
  }
  __shared__ float red[4][256];
  red[0][threadIdx.x] = a0; red[1][threadIdx.x] = a1;
  red[2][threadIdx.x] = a2; red[3][threadIdx.x] = a3;
  __syncthreads();
  for (int s = 128; s > 0; s >>= 1) {
    if (threadIdx.x < s) {
      red[0][threadIdx.x] += red[0][threadIdx.x + s];
      red[1][threadIdx.x] += red[1][threadIdx.x + s];
      red[2][threadIdx.x] += red[2][threadIdx.x + s];
      red[3][threadIdx.x] += red[3][threadIdx.x + s];
    }
    __syncthreads();
  }
  if (threadIdx.x < 4) {
    const float val = red[threadIdx.x][0] + (half == 0 ? bg[threadIdx.x] : 0.f);
    (half ? G1 : G0)[(size_t)v * 4 + threadIdx.x] = val;
  }
}

// ---------------- W2 [4][1024][128] f32 -> W2T [128 o][4096 k] bf16 ----------------
__global__ void prep_w2(const float* __restrict__ W2, unsigned short* __restrict__ W2T) {
  __shared__ float st[64][65];
  const int kt = blockIdx.x, ot = blockIdx.y;
  const int tid = threadIdx.x;
  for (int it = 0; it < 16; ++it) {
    const int idx = it * 256 + tid;
    const int k = idx >> 6, o = idx & 63;
    st[k][o] = W2[(size_t)(kt * 64 + k) * 128 + ot * 64 + o];
  }
  __syncthreads();
  for (int it = 0; it < 4; ++it) {
    const int idx = it * 256 + tid;
    const int o = idx >> 4, c = idx & 15;
    const unsigned int p0 =
        (unsigned int)f2b(st[c * 4 + 0][o]) | ((unsigned int)f2b(st[c * 4 + 1][o]) << 16);
    const unsigned int p1 =
        (unsigned int)f2b(st[c * 4 + 2][o]) | ((unsigned int)f2b(st[c * 4 + 3][o]) << 16);
    *(uint2*)(W2T + (size_t)(ot * 64 + o) * 4096 + kt * 64 + c * 4) = make_uint2(p0, p1);
  }
}

// ---------------- emb f32 -> bf16 tables E0/E1 [512][1024] ----------------
__global__ void prep_emb(const float* __restrict__ emb0, const float* __restrict__ emb1,
                         unsigned short* __restrict__ E0, unsigned short* __restrict__ E1) {
  const float* __restrict__ src = blockIdx.y ? emb1 : emb0;
  unsigned short* __restrict__ dst = blockIdx.y ? E1 : E0;
  const size_t base = (size_t)blockIdx.x * 2048 + (size_t)threadIdx.x * 8;
  const float4 lo = *(const float4*)(src + base);
  const float4 hi = *(const float4*)(src + base + 4);
  short8 o;
  o[0] = (short)f2b(lo.x); o[1] = (short)f2b(lo.y);
  o[2] = (short)f2b(lo.z); o[3] = (short)f2b(lo.w);
  o[4] = (short)f2b(hi.x); o[5] = (short)f2b(hi.y);
  o[6] = (short)f2b(hi.z); o[7] = (short)f2b(hi.w);
  *(short8*)(dst + base) = o;
}

// ---------------- W1 [4][2048][1024] f32 -> W1T bf16 [8 z][1024 d][1024 k] ----------------
__global__ void prep_w1t(const float* __restrict__ W1, unsigned short* __restrict__ W1T) {
  __shared__ float st[64][65];
  const int z = blockIdx.y;            // e*2 + half
  const int kt = blockIdx.x >> 4, dt = blockIdx.x & 15;
  const int e = z >> 1, half = z & 1;
  const int tid = threadIdx.x;
  const int r = tid >> 2, cg = (tid & 3) * 16;
  const float* src = W1 + ((size_t)e * 2048 + half * 1024 + kt * 64 + r) * 1024 + dt * 64 + cg;
#pragma unroll
  for (int j = 0; j < 4; ++j) {
    const float4 v = *(const float4*)(src + j * 4);
    st[r][cg + j * 4 + 0] = v.x; st[r][cg + j * 4 + 1] = v.y;
    st[r][cg + j * 4 + 2] = v.z; st[r][cg + j * 4 + 3] = v.w;
  }
  __syncthreads();
  // write transposed: W1T[z][dt*64 + dr][kt*64 + kc]
  const int dr = tid >> 2, kb = (tid & 3) * 16;
  short8 o0, o1;
#pragma unroll
  for (int m = 0; m < 8; ++m) o0[m] = (short)f2b(st[kb + m][dr]);
#pragma unroll
  for (int m = 0; m < 8; ++m) o1[m] = (short)f2b(st[kb + 8 + m][dr]);
  unsigned short* dst = W1T + ((size_t)z * 1024 + dt * 64 + dr) * 1024 + kt * 64 + kb;
  *(short8*)dst = o0;
  *(short8*)(dst + 8) = o1;
}

// ---------------- expert tables: per z, (512v x 1024k) @ (1024k x 1024d) ----------------
// tiles BM=128(v) x BN=64(d), BK=64; grid 512 = z8 * vt4 * dt16; 256 thr, 4 waves
__launch_bounds__(256, 2)
__global__ void build_tables(const unsigned short* __restrict__ E0,
                             const unsigned short* __restrict__ E1,
                             const unsigned short* __restrict__ W1T,
                             const float* __restrict__ b1,
                             unsigned short* __restrict__ T0, unsigned short* __restrict__ T1) {
  __shared__ unsigned short At[128 * 64];  // [v][k] swizzled, 16KB
  __shared__ unsigned short Bt[64 * 64];   // [d][k] swizzled, 8KB

  const int bid = blockIdx.x;
  const int z = bid >> 6, rem = bid & 63;
  const int vt = rem >> 4, dt = rem & 15;
  const int e = z >> 1, half = z & 1;
  const unsigned short* __restrict__ E = half ? E1 : E0;
  const unsigned short* __restrict__ Wp = W1T + (size_t)z * 1024 * 1024;
  unsigned short* __restrict__ Tout = (half ? T1 : T0) + (size_t)e * 512 * 1024;

  const int tid = threadIdx.x, lane = tid & 63, wave = tid >> 6;
  const int wm = wave >> 1, wn = wave & 1;

  // A staging: 2 thr/row, 64B each
  const int arow = tid >> 1, ah = tid & 1;
  int wAoff[4];
#pragma unroll
  for (int i = 0; i < 4; ++i)
    wAoff[i] = arow * 128 + ((ah * 64 + i * 16) ^ ((arow & 7) << 4));
  // B staging: 4 thr/col, 32B each
  const int bcol = tid >> 2, bc = tid & 3;
  int wBoff[2];
#pragma unroll
  for (int i = 0; i < 2; ++i)
    wBoff[i] = bcol * 128 + ((bc * 32 + i * 16) ^ ((bcol & 7) << 4));

  const unsigned short* aSrc = E + (size_t)(vt * 128 + arow) * 1024 + ah * 32;
  const unsigned short* bSrc = Wp + (size_t)(dt * 64 + bcol) * 1024 + bc * 16;

  const int kq = (lane >> 4) * 16;
  int rAoff[4], rAsw[4], rBoff[2], rBsw[2];
#pragma unroll
  for (int mi = 0; mi < 4; ++mi) {
    const int ra = wm * 64 + mi * 16 + (lane & 15);
    rAoff[mi] = ra * 128; rAsw[mi] = (ra & 7) << 4;
  }
#pragma unroll
  for (int ni = 0; ni < 2; ++ni) {
    const int cb = wn * 32 + ni * 16 + (lane & 15);
    rBoff[ni] = cb * 128; rBsw[ni] = (cb & 7) << 4;
  }

  f32x4 acc[4][2] = {};
  uint4 ea[4]; uint4 eb[2];

  auto issueLoads = [&](int kt2) {
    const int k0 = kt2 * 64;
#pragma unroll
    for (int i = 0; i < 4; ++i) ea[i] = *(const uint4*)(aSrc + k0 + i * 8);
#pragma unroll
    for (int i = 0; i < 2; ++i) eb[i] = *(const uint4*)(bSrc + k0 + i * 8);
  };

  issueLoads(0);
  for (int kt2 = 0; kt2 < 16; ++kt2) {
    BARRIER();  // prior frag reads done
#pragma unroll
    for (int i = 0; i < 4; ++i) *(uint4*)((char*)At + wAoff[i]) = ea[i];
#pragma unroll
    for (int i = 0; i < 2; ++i) *(uint4*)((char*)Bt + wBoff[i]) = eb[i];
    if (kt2 < 15) issueLoads(kt2 + 1);
    BARRIER();  // writes visible
#pragma unroll
    for (int kk = 0; kk < 2; ++kk) {
      const int kb = kk * 64 + kq;
      short8 af[4], bfr[2];
#pragma unroll
      for (int mi = 0; mi < 4; ++mi)
        af[mi] = *(const short8*)((char*)At + rAoff[mi] + (kb ^ rAsw[mi]));
#pragma unroll
      for (int ni = 0; ni < 2; ++ni)
        bfr[ni] = *(const short8*)((char*)Bt + rBoff[ni] + (kb ^ rBsw[ni]));
#pragma unroll
      for (int mi = 0; mi < 4; ++mi)
#pragma unroll
        for (int ni = 0; ni < 2; ++ni)
          acc[mi][ni] = __builtin_amdgcn_mfma_f32_16x16x32_bf16(af[mi], bfr[ni], acc[mi][ni], 0, 0, 0);
    }
  }
  // epilogue: + b1 (half 0 only), bf16 store
  const float* bb = b1 + (size_t)e * 1024;
#pragma unroll
  for (int ni = 0; ni < 2; ++ni) {
    const int dcol = dt * 64 + wn * 32 + ni * 16 + (lane & 15);
    const float bias = (half == 0) ? bb[dcol] : 0.f;
#pragma unroll
    for (int mi = 0; mi < 4; ++mi) {
      const int vrow0 = vt * 128 + wm * 64 + mi * 16 + ((lane >> 4) << 2);
      const f32x4 a = acc[mi][ni];
#pragma unroll
      for (int j = 0; j < 4; ++j)
        Tout[(size_t)(vrow0 + j) * 1024 + dcol] = f2b(a[j] + bias);
    }
  }
}

// ---------------- main fused kernel: gather + silu + gate + GEMM ----------------
// BM=128 tokens, BN=128 out, BK=64; 512 thr (8 waves: wm4 x wn2, mi=2, ni=4)
__launch_bounds__(512, 4)
__global__ void moe_main(const int* __restrict__ X,
                         const unsigned short* __restrict__ T0,
                         const unsigned short* __restrict__ T1,
                         const unsigned short* __restrict__ W2T,
                         const float* __restrict__ G0,
                         const float* __restrict__ G1,
                         const float* __restrict__ b2v,
                         float* __restrict__ out) {
  __shared__ unsigned short At[128 * 64];  // 16KB, swizzled
  __shared__ unsigned short Bt[128 * 64];  // 16KB, swizzled
  __shared__ float gl[128 * 4];
  __shared__ int xs0[128], xs1[128];

  const int tid = threadIdx.x, lane = tid & 63, wave = tid >> 6;
  const int wm = wave >> 1, wn = wave & 1;
  int bid = blockIdx.x;
  bid = (bid & 7) * 64 + (bid >> 3);  // XCD swizzle (512 % 8 == 0)
  const int b0 = bid * 128;

  if (tid < 128) {
    const int b = b0 + tid;
    const int x0 = X[2 * b], x1 = X[2 * b + 1];
    xs0[tid] = x0; xs1[tid] = x1;
    const float4 l0 = *(const float4*)(G0 + 4 * x0);
    const float4 l1 = *(const float4*)(G1 + 4 * x1);
    const float z0 = l0.x + l1.x, z1 = l0.y + l1.y;
    const float z2 = l0.z + l1.z, z3 = l0.w + l1.w;
    const float m = fmaxf(fmaxf(z0, z1), fmaxf(z2, z3));
    const float e0 = __expf(z0 - m), e1 = __expf(z1 - m);
    const float e2 = __expf(z2 - m), e3 = __expf(z3 - m);
    const float inv = __builtin_amdgcn_rcpf(e0 + e1 + e2 + e3);
    *(float4*)(&gl[4 * tid]) = make_float4(e0 * inv, e1 * inv, e2 * inv, e3 * inv);
  }
  __syncthreads();

  // staging coords: 4 thr/row, 32B each (A and B share the pattern; Bt rows = out cols)
  const int arow = tid >> 2, ac = tid & 3;
  const int sx0 = xs0[arow], sx1 = xs1[arow];
  const float4 grow = *(const float4*)(&gl[4 * arow]);
  int wOff[2];
#pragma unroll
  for (int i = 0; i < 2; ++i)
    wOff[i] = arow * 128 + ((ac * 32 + i * 16) ^ ((arow & 7) << 4));

  // frag read offsets
  const int kq = (lane >> 4) * 16;
  int rAoff[2], rAsw[2], rBoff[4], rBsw[4];
#pragma unroll
  for (int mi = 0; mi < 2; ++mi) {
    const int ra = wm * 32 + mi * 16 + (lane & 15);
    rAoff[mi] = ra * 128; rAsw[mi] = (ra & 7) << 4;
  }
#pragma unroll
  for (int ni = 0; ni < 4; ++ni) {
    const int cb = wn * 64 + ni * 16 + (lane & 15);
    rBoff[ni] = cb * 128; rBsw[ni] = (cb & 7) << 4;
  }

  f32x4 acc[2][4] = {};
  uint4 ua[2], ub[2], bw[2];

  auto issueLoads = [&](int t) {
    const int e = t >> 4, d0 = (t & 15) << 6;
    const unsigned short* p0 = T0 + (((size_t)(e * 512 + sx0)) << 10) + d0 + ac * 16;
    const unsigned short* p1 = T1 + (((size_t)(e * 512 + sx1)) << 10) + d0 + ac * 16;
    const unsigned short* pb = W2T + (size_t)arow * 4096 + t * 64 + ac * 16;
    ua[0] = *(const uint4*)p0; ua[1] = *(const uint4*)(p0 + 8);
    ub[0] = *(const uint4*)p1; ub[1] = *(const uint4*)(p1 + 8);
    bw[0] = *(const uint4*)pb; bw[1] = *(const uint4*)(pb + 8);
  };

  issueLoads(0);
  for (int t = 0; t < 64; ++t) {
    const int e = t >> 4;
    const float g = (e == 0) ? grow.x : (e == 1) ? grow.y : (e == 2) ? grow.z : grow.w;
    short8 sa[2];
#pragma unroll
    for (int i = 0; i < 2; ++i) {
      float f[8];
      f[0] = bflo(ua[i].x) + bflo(ub[i].x);
      f[1] = bfhi(ua[i].x) + bfhi(ub[i].x);
      f[2] = bflo(ua[i].y) + bflo(ub[i].y);
      f[3] = bfhi(ua[i].y) + bfhi(ub[i].y);
      f[4] = bflo(ua[i].z) + bflo(ub[i].z);
      f[5] = bfhi(ua[i].z) + bfhi(ub[i].z);
      f[6] = bflo(ua[i].w) + bflo(ub[i].w);
      f[7] = bfhi(ua[i].w) + bfhi(ub[i].w);
      short8 o8;
#pragma unroll
      for (int j = 0; j < 8; ++j) {
        const float tv = f[j];
        const float sg = g * tv * __builtin_amdgcn_rcpf(1.f + __expf(-tv));  // g*silu
        o8[j] = (short)f2b(sg);
      }
      sa[i] = o8;
    }
    BARRIER();  // #1: all waves' frag reads of previous tile complete
    *(uint4*)((char*)At + wOff[0]) = *(uint4*)&sa[0];
    *(uint4*)((char*)At + wOff[1]) = *(uint4*)&sa[1];
    *(uint4*)((char*)Bt + wOff[0]) = bw[0];
    *(uint4*)((char*)Bt + wOff[1]) = bw[1];
    if (t < 63) issueLoads(t + 1);  // stays in flight across raw barrier
    BARRIER();  // #2: writes visible
#pragma unroll
    for (int kk = 0; kk < 2; ++kk) {
      const int kb = kk * 64 + kq;
      short8 af[2], bfr[4];
#pragma unroll
      for (int mi = 0; mi < 2; ++mi)
        af[mi] = *(const short8*)((char*)At + rAoff[mi] + (kb ^ rAsw[mi]));
#pragma unroll
      for (int ni = 0; ni < 4; ++ni)
        bfr[ni] = *(const short8*)((char*)Bt + rBoff[ni] + (kb ^ rBsw[ni]));
#pragma unroll
      for (int mi = 0; mi < 2; ++mi)
#pragma unroll
        for (int ni = 0; ni < 4; ++ni)
          acc[mi][ni] = __builtin_amdgcn_mfma_f32_16x16x32_bf16(af[mi], bfr[ni], acc[mi][ni], 0, 0, 0);
    }
  }

  // epilogue: + sum_e g_e*b2[e][o]
#pragma unroll
  for (int ni = 0; ni < 4; ++ni) {
    const int col = wn * 64 + ni * 16 + (lane & 15);
    const float c0 = b2v[col], c1 = b2v[128 + col];
    const float c2 = b2v[256 + col], c3 = b2v[384 + col];
#pragma unroll
    for (int mi = 0; mi < 2; ++mi) {
      const int row0 = wm * 32 + mi * 16 + ((lane >> 4) << 2);
      const f32x4 a = acc[mi][ni];
#pragma unroll
      for (int j = 0; j < 4; ++j) {
        const int row = row0 + j;
        const float4 g = *(const float4*)(&gl[4 * row]);
        out[(size_t)(b0 + row) * 128 + col] = a[j] + g.x * c0 + g.y * c1 + g.z * c2 + g.w * c3;
      }
    }
  }
}

extern "C" void kernel_launch(void* const* d_in, const int* in_sizes, int n_in,
                              void* d_out, int out_size, void* d_ws, size_t ws_size,
                              hipStream_t stream) {
  const int*   X    = (const int*)  d_in[0];
  const float* emb0 = (const float*)d_in[1];
  const float* emb1 = (const float*)d_in[2];
  const float* W1   = (const float*)d_in[3];
  const float* b1   = (const float*)d_in[4];
  const float* W2   = (const float*)d_in[5];
  const float* b2   = (const float*)d_in[6];
  const float* Wg   = (const float*)d_in[7];
  const float* bg   = (const float*)d_in[8];
  float* out = (float*)d_out;

  char* ws = (char*)d_ws;
  const size_t MB = 1024 * 1024;
  unsigned short* T0  = (unsigned short*)(ws);             // 4 MB
  unsigned short* T1  = (unsigned short*)(ws + 4 * MB);    // 4 MB
  unsigned short* W2T = (unsigned short*)(ws + 8 * MB);    // 1 MB
  float* G0 = (float*)(ws + 9 * MB);                       // 8 KB
  float* G1 = (float*)(ws + 9 * MB + 8192);                // 8 KB
  unsigned short* E0  = (unsigned short*)(ws + 10 * MB);   // 1 MB
  unsigned short* E1  = (unsigned short*)(ws + 11 * MB);   // 1 MB
  unsigned short* W1T = (unsigned short*)(ws + 12 * MB);   // 16 MB

  hipLaunchKernelGGL(prep_emb, dim3(256, 2), dim3(256), 0, stream, emb0, emb1, E0, E1);
  hipLaunchKernelGGL(prep_w1t, dim3(256, 8), dim3(256), 0, stream, W1, W1T);
  hipLaunchKernelGGL(prep_w2, dim3(64, 2), dim3(256), 0, stream, W2, W2T);
  hipLaunchKernelGGL(prep_g, dim3(1024), dim3(256), 0, stream, emb0, emb1, Wg, bg, G0, G1);
  hipLaunchKernelGGL(build_tables, dim3(512), dim3(256), 0, stream, E0, E1, W1T, b1, T0, T1);
  hipLaunchKernelGGL(moe_main, dim3(512), dim3(512), 0, stream, X, T0, T1, W2T, G0, G1, b2, out);
}